// Round 2
// baseline (31760.193 us; speedup 1.0000x reference)
//
#include <hip/hip_runtime.h>

// 6 chained LSTM passes (layers 0-4 share W1/U1/b1, layer 5 uses W2/U2/b2).
// B=128, T=256, H=512, f32 I/O. Persistent kernel, 256 wgs:
//   4 independent row-groups (32 batch rows) x 64 col-groups (8 units = 32 z-cols).
// Weights f16 in 64KB LDS (XOR-swizzled); activations f16 in a 257-slot circular
// seq buffer in ws; gates/c-state f32; per-step 64-wg rowgroup barrier.

#define TSEQ  256
#define HID   512
#define SLOTS 257
#define NWGR  64      // wgs per rowgroup barrier

typedef _Float16 v8h __attribute__((ext_vector_type(8)));
typedef float    v4f __attribute__((ext_vector_type(4)));

__device__ __forceinline__ float sigm(float x)  { return 1.0f / (1.0f + __expf(-x)); }
__device__ __forceinline__ float tanhf_(float x){ return 1.0f - 2.0f / (__expf(2.0f * x) + 1.0f); }

// Rowgroup barrier: arrive/poll by thread 0; tid0's __threadfence covers the whole
// wg (same CU -> same L1/L2); __syncthreads drains vmcnt before arrival.
__device__ __forceinline__ void groupbar(unsigned* cnt, unsigned* gen) {
    __syncthreads();
    if (threadIdx.x == 0) {
        __threadfence();   // release: wb L2 (agent scope)
        unsigned g = __hip_atomic_load(gen, __ATOMIC_RELAXED, __HIP_MEMORY_SCOPE_AGENT);
        unsigned a = __hip_atomic_fetch_add(cnt, 1u, __ATOMIC_ACQ_REL, __HIP_MEMORY_SCOPE_AGENT);
        if (a == NWGR - 1) {
            __hip_atomic_store(cnt, 0u, __ATOMIC_RELAXED, __HIP_MEMORY_SCOPE_AGENT);
            __hip_atomic_fetch_add(gen, 1u, __ATOMIC_RELEASE, __HIP_MEMORY_SCOPE_AGENT);
        } else {
            while (__hip_atomic_load(gen, __ATOMIC_RELAXED, __HIP_MEMORY_SCOPE_AGENT) == g)
                __builtin_amdgcn_s_sleep(2);
        }
        __threadfence();   // acquire: inv L1 + stale L2
    }
    __syncthreads();
}

__global__ __launch_bounds__(256)
void lstm_persist(const float* __restrict__ x,
                  const float* __restrict__ W1, const float* __restrict__ U1,
                  const float* __restrict__ b1,
                  const float* __restrict__ W2, const float* __restrict__ U2,
                  const float* __restrict__ b2,
                  float* __restrict__ out,
                  _Float16* __restrict__ Sh,
                  const _Float16* __restrict__ zbuf,
                  unsigned* __restrict__ bar) {
    const int wg   = blockIdx.x;
    const int r    = (wg & 7) >> 1;                  // rowgroup 0..3 (XCD pair)
    const int cg   = ((wg >> 3) << 1) | (wg & 1);    // col-group 0..63
    const int tid  = threadIdx.x;
    const int lane = tid & 63;
    const int wv   = tid >> 6;
    const int rw   = wv >> 1;                        // row half 0/1
    const int cw   = wv & 1;                         // col half 0/1

    __shared__ _Float16 Wl[32 * 1024];               // exactly 64 KB, XOR-swizzled

    // MFMA A mapping: row = lane&15, k = (lane>>4)*8 + j
    const int q     = lane >> 4;
    const int koffA = q << 3;
    const int arow  = (r << 5) + (rw << 4) + (lane & 15);   // global batch row for A
    // B mapping: local z-col
    const int cB  = (cw << 4) + (lane & 15);                 // 0..31
    const int c7  = cB & 7;
    _Float16* const Bbase = Wl + (cB << 10);                 // cB*128 16B-units *8 elems

    // epilogue ownership after 4x4 quad transpose: row q*4+j, unit uu=(lane&15)>>2
    const int j4   = lane & 3;
    const int erow = (r << 5) + (rw << 4) + (q << 2) + j4;   // global row
    const int eun  = (cg << 3) + (cw << 2) + ((lane & 15) >> 2);  // global unit

    unsigned* const cnt = bar + (r << 6);
    unsigned* const gen = bar + (r << 6) + 32;

    float cst = 0.0f;
    float bI = 0.f, bF = 0.f, bG = 0.f, bO = 0.f;

    for (int m = 0; m < 6; ++m) {
        if (m == 0 || m == 5) {
            const float* Wg = m ? W2 : W1;
            const float* Ug = m ? U2 : U1;
            const float* bg = m ? b2 : b1;
            // stage 32 z-cols x 1024 k as f16 into LDS (XOR swizzle on 16B units)
            for (int idx = tid; idx < 4096; idx += 256) {
                const int c  = idx >> 7;        // local z-col (unit-major: c = u*4+g)
                const int k8 = idx & 127;       // 16B unit along k
                const int colg = ((c & 3) << 9) + (cg << 3) + (c >> 2);
                const float* src = (k8 < 64) ? (Wg + ((k8 << 3) * 2048 + colg))
                                             : (Ug + (((k8 - 64) << 3) * 2048 + colg));
                v8h v;
                #pragma unroll
                for (int j = 0; j < 8; ++j) v[j] = (_Float16)src[j * 2048];
                const int u16 = (c << 7) + (k8 ^ (c & 7));
                *(v8h*)(Wl + (u16 << 3)) = v;
            }
            bI = bg[eun]; bF = bg[512 + eun]; bG = bg[1024 + eun]; bO = bg[1536 + eun];
            __syncthreads();
        }

        for (int t = 0; t < TSEQ; ++t) {
            int sx = t - m;     if (sx < 0) sx += SLOTS;   // x-read slot (m>=1)
            int sh = t - m - 2; if (sh < 0) sh += SLOTS;   // h-read slot
            int sw = t - m - 1; if (sw < 0) sw += SLOTS;   // h-write slot

            v4f acc = {0.f, 0.f, 0.f, 0.f};

            // ---- x part (k = 0..511) ----
            if (m == 0) {
                const float* xp = x + ((arow * TSEQ + t) * HID) + koffA;
                #pragma unroll
                for (int kc = 0; kc < 16; ++kc) {
                    const float4 f0 = *(const float4*)(xp + (kc << 5));
                    const float4 f1 = *(const float4*)(xp + (kc << 5) + 4);
                    v8h a;
                    a[0] = (_Float16)f0.x; a[1] = (_Float16)f0.y;
                    a[2] = (_Float16)f0.z; a[3] = (_Float16)f0.w;
                    a[4] = (_Float16)f1.x; a[5] = (_Float16)f1.y;
                    a[6] = (_Float16)f1.z; a[7] = (_Float16)f1.w;
                    const v8h b = *(const v8h*)(Bbase + ((((kc << 2) + q) ^ c7) << 3));
                    acc = __builtin_amdgcn_mfma_f32_16x16x32_f16(a, b, acc, 0, 0, 0);
                }
            } else {
                const _Float16* xp = Sh + (size_t)(arow * SLOTS + sx) * HID + koffA;
                #pragma unroll
                for (int kc = 0; kc < 16; ++kc) {
                    const v8h a = *(const v8h*)(xp + (kc << 5));
                    const v8h b = *(const v8h*)(Bbase + ((((kc << 2) + q) ^ c7) << 3));
                    acc = __builtin_amdgcn_mfma_f32_16x16x32_f16(a, b, acc, 0, 0, 0);
                }
            }

            // ---- h part (k = 512..1023) ----
            const _Float16* hp = (m == 0 && t == 0)
                                     ? (zbuf + koffA)
                                     : (Sh + (size_t)(arow * SLOTS + sh) * HID + koffA);
            #pragma unroll
            for (int kc = 0; kc < 16; ++kc) {
                const v8h a = *(const v8h*)(hp + (kc << 5));
                const v8h b = *(const v8h*)(Bbase + (((64 + (kc << 2) + q) ^ c7) << 3));
                acc = __builtin_amdgcn_mfma_f32_16x16x32_f16(a, b, acc, 0, 0, 0);
            }

            // ---- 4x4 transpose within quads (reg p <-> lane&3) via shfl_xor ----
            float M0 = acc[0], M1 = acc[1], M2 = acc[2], M3 = acc[3];
            {   // mask 1
                float t0 = __shfl_xor(M1, 1, 64);
                float t1 = __shfl_xor(M0, 1, 64);
                float t2 = __shfl_xor(M3, 1, 64);
                float t3 = __shfl_xor(M2, 1, 64);
                if (j4 & 1) { M0 = t0; M2 = t2; } else { M1 = t1; M3 = t3; }
            }
            {   // mask 2
                float t0 = __shfl_xor(M2, 2, 64);
                float t1 = __shfl_xor(M3, 2, 64);
                float t2 = __shfl_xor(M0, 2, 64);
                float t3 = __shfl_xor(M1, 2, 64);
                if (j4 & 2) { M0 = t0; M1 = t1; } else { M2 = t2; M3 = t3; }
            }
            // lane now holds gates [i,f,g,o] (M0..M3) for (erow, eun)

            const float ig = sigm(M0 + bI);
            const float fg = sigm(M1 + bF);
            const float gg = tanhf_(M2 + bG);
            const float og = sigm(M3 + bO);
            cst = fg * cst + ig * gg;
            const float h = og * tanhf_(cst);

            Sh[(size_t)(erow * SLOTS + sw) * HID + eun] = (_Float16)h;
            if (m == 5 && t == TSEQ - 1) out[erow * HID + eun] = h;

            groupbar(cnt, gen);
        }
    }
}

extern "C" void kernel_launch(void* const* d_in, const int* in_sizes, int n_in,
                              void* d_out, int out_size, void* d_ws, size_t ws_size,
                              hipStream_t stream) {
    (void)in_sizes; (void)n_in; (void)out_size;
    const size_t SZ_SH   = (size_t)128 * SLOTS * HID * sizeof(_Float16); // 33,685,504
    const size_t OFF_Z   = SZ_SH;          // 4 KB zero buffer (already 4K-aligned)
    const size_t OFF_BAR = OFF_Z + 4096;   // 4 KB barrier region
    const size_t NEED    = OFF_BAR + 4096;
    if (ws_size < NEED) return;

    char* ws = (char*)d_ws;
    hipMemsetAsync(ws + OFF_Z, 0, 8192, stream);  // zero buf + barriers

    lstm_persist<<<256, 256, 0, stream>>>(
        (const float*)d_in[0],
        (const float*)d_in[1], (const float*)d_in[2], (const float*)d_in[3],
        (const float*)d_in[4], (const float*)d_in[5], (const float*)d_in[6],
        (float*)d_out,
        (_Float16*)ws,
        (const _Float16*)(ws + OFF_Z),
        (unsigned*)(ws + OFF_BAR));
}